// Round 3
// baseline (1768.081 us; speedup 1.0000x reference)
//
#include <hip/hip_runtime.h>
#include <hip/hip_bf16.h>
#include <float.h>

#define BB 512
#define TT 40
#define CC 512
#define HH 512

typedef short bf16x8 __attribute__((ext_vector_type(8)));
typedef float f32x4 __attribute__((ext_vector_type(4)));
typedef unsigned short ushortx8 __attribute__((ext_vector_type(8)));

__device__ __forceinline__ unsigned short f2bf(float f){
  union { float f; unsigned int i; } v; v.f = f;
  unsigned int r = v.i + 0x7fffu + ((v.i >> 16) & 1u);
  return (unsigned short)(r >> 16);
}

// one wave per (b,t): convert 512 floats -> bf16, compute nonzero mask
__global__ void prep_x_kernel(const float* __restrict__ x, unsigned short* __restrict__ xb,
                              float* __restrict__ mask){
  int w = blockIdx.x*4 + (threadIdx.x>>6);
  int lane = threadIdx.x & 63;
  const float* src = x + (size_t)w*CC + lane*8;
  f32x4 a = *(const f32x4*)(src);
  f32x4 b = *(const f32x4*)(src+4);
  ushortx8 o;
  o[0]=f2bf(a[0]); o[1]=f2bf(a[1]); o[2]=f2bf(a[2]); o[3]=f2bf(a[3]);
  o[4]=f2bf(b[0]); o[5]=f2bf(b[1]); o[6]=f2bf(b[2]); o[7]=f2bf(b[3]);
  *(ushortx8*)(xb + (size_t)w*CC + lane*8) = o;
  bool nz = (a[0]!=0.f)||(a[1]!=0.f)||(a[2]!=0.f)||(a[3]!=0.f)||
            (b[0]!=0.f)||(b[1]!=0.f)||(b[2]!=0.f)||(b[3]!=0.f);
  unsigned long long bal = __ballot(nz);
  if (lane==0) mask[w] = bal ? 1.0f : 0.0f;
}

__global__ void cvt_kernel(const float* __restrict__ src, unsigned short* __restrict__ dst, int n){
  int i = blockIdx.x*blockDim.x + threadIdx.x;
  if (i < n) dst[i] = f2bf(src[i]);
}

// zero all h buffers (2dir x 2buf x 512 x 512, f32 + bf16) and the 8 group counters.
__global__ void init_h_kernel(float* __restrict__ h32, unsigned short* __restrict__ hb,
                              unsigned int* __restrict__ ctr){
  int i = blockIdx.x*blockDim.x + threadIdx.x;
  h32[i] = 0.f;
  hb[i] = 0;
  if (i < 8) ctr[i*32] = 0u;
}

// Persistent GRU, normal launch, 256 WGs x 256 threads.
// WG = (grp = bid>>5 -> dir, 128-row b-slab; strip = bid&31 -> 16 h cols).
// The h recurrence closes within each 32-WG group -> group-local atomic barrier.
// Consecutive-bid groups: whole resident groups always finish & exit, so forward
// progress holds even if <256 WGs are co-resident (no grid-wide co-residency needed).
__global__ __launch_bounds__(256) void gru_persist_kernel(
    const unsigned short* __restrict__ xb,
    const unsigned short* __restrict__ wihF, const unsigned short* __restrict__ whhF,
    const unsigned short* __restrict__ wihB, const unsigned short* __restrict__ whhB,
    const float* __restrict__ bihF, const float* __restrict__ bhhF,
    const float* __restrict__ bihB, const float* __restrict__ bhhB,
    const float* __restrict__ mask,
    float* __restrict__ h32, unsigned short* __restrict__ hb,
    float* __restrict__ out, unsigned int* __restrict__ ctr)
{
  const int bid   = blockIdx.x;
  const int grp   = bid >> 5;      // 0..7 : consecutive bids -> deadlock-safe groups
  const int strip = bid & 31;      // 0..31
  const int dir   = grp >> 2;      // 0..1
  const int bslab = grp & 3;       // 0..3
  const int b0 = bslab * 128;
  const int n0 = strip * 16;
  unsigned int* myctr = ctr + grp*32;   // 128B-strided counters

  const unsigned short* wih = dir ? wihB : wihF;
  const unsigned short* whh = dir ? whhB : whhF;
  const float* bih = dir ? bihB : bihF;
  const float* bhh = dir ? bhhB : bhhF;

  const int tid  = threadIdx.x;
  const int lane = tid & 63;
  const int lr   = lane & 15;       // fragment row/col index
  const int lkg  = lane >> 4;       // 0..3 k-group
  const int wv   = tid >> 6;        // wave 0..3
  const int wrow = wv * 32;         // wave's first batch row within slab

  // ---- LDS weight strip: rows 0-15 = r gate, 16-31 = z, 32-47 = n; K fused [Wih|Whh]
  __shared__ __align__(16) unsigned short wlds[48 * 1024];  // 96 KB
  for (int q = tid; q < 6144; q += 256) {        // 6144 16B-chunks
    const int row = q >> 7;                      // 0..47
    const int kc  = (q & 127) * 8;               // element k 0..1023
    const int g   = row >> 4;
    const int c   = row & 15;
    const unsigned short* src =
        (kc < 512 ? wih : whh) + ((size_t)(g*HH + n0 + c))*512 + (kc & 511);
    const int kb = kc * 2;
    *(ushortx8*)((char*)wlds + row*2048 + (kb ^ ((row & 7) << 4))) =
        *(const ushortx8*)src;
  }
  __syncthreads();

  // per-lane biases for column jj
  const int jj = n0 + lr;
  const float br  = bih[jj]        + bhh[jj];
  const float bz  = bih[HH + jj]   + bhh[HH + jj];
  const float bnx = bih[2*HH + jj];
  const float bnh = bhh[2*HH + jj];

  float omax[2][4];
  #pragma unroll
  for (int mf=0; mf<2; ++mf)
    #pragma unroll
    for (int j=0; j<4; ++j) omax[mf][j] = -FLT_MAX;

  const int swz = (lr & 7) << 4;

  for (int t = 0; t < TT; ++t) {
    const int tx = dir ? (TT-1-t) : t;
    const int bi = t & 1;
    const float* h32in           = h32 + (size_t)(dir*2 + bi)      * (BB*HH);
    float* h32out                = h32 + (size_t)(dir*2 + (bi^1))  * (BB*HH);
    const unsigned short* hbin   = hb  + (size_t)(dir*2 + bi)      * (BB*HH);
    unsigned short* hbout        = hb  + (size_t)(dir*2 + (bi^1))  * (BB*HH);

    f32x4 ar[2], az[2], anx[2], anh[2];
    #pragma unroll
    for (int mf=0; mf<2; ++mf){ ar[mf]=0.f; az[mf]=0.f; anx[mf]=0.f; anh[mf]=0.f; }

    // per-lane A row base pointers
    const unsigned short* xr0 = xb + ((size_t)(b0 + wrow + lr     )*TT + tx)*CC;
    const unsigned short* xr1 = xb + ((size_t)(b0 + wrow + 16 + lr)*TT + tx)*CC;
    const unsigned short* hr0 = hbin + (size_t)(b0 + wrow + lr     )*HH;
    const unsigned short* hr1 = hbin + (size_t)(b0 + wrow + 16 + lr)*HH;
    const char* wbase = (const char*)wlds + lr*2048;

    // ---- x-part: K = 0..511 -> acc r, z, nx (independent of the barrier's h)
    #pragma unroll
    for (int kk = 0; kk < 16; ++kk) {
      const int ko = kk*32 + lkg*8;
      bf16x8 a0 = *(const bf16x8*)(xr0 + ko);
      bf16x8 a1 = *(const bf16x8*)(xr1 + ko);
      const int kbx = (ko*2) ^ swz;
      bf16x8 brf = *(const bf16x8*)(wbase +         kbx);
      bf16x8 bzf = *(const bf16x8*)(wbase + 32768 + kbx);
      bf16x8 bnf = *(const bf16x8*)(wbase + 65536 + kbx);
      ar[0]  = __builtin_amdgcn_mfma_f32_16x16x32_bf16(a0, brf, ar[0],0,0,0);
      ar[1]  = __builtin_amdgcn_mfma_f32_16x16x32_bf16(a1, brf, ar[1],0,0,0);
      az[0]  = __builtin_amdgcn_mfma_f32_16x16x32_bf16(a0, bzf, az[0],0,0,0);
      az[1]  = __builtin_amdgcn_mfma_f32_16x16x32_bf16(a1, bzf, az[1],0,0,0);
      anx[0] = __builtin_amdgcn_mfma_f32_16x16x32_bf16(a0, bnf, anx[0],0,0,0);
      anx[1] = __builtin_amdgcn_mfma_f32_16x16x32_bf16(a1, bnf, anx[1],0,0,0);
    }
    // ---- h-part: K = 512..1023 -> acc r, z, nh
    #pragma unroll
    for (int kk = 0; kk < 16; ++kk) {
      const int ko = kk*32 + lkg*8;
      bf16x8 a0 = *(const bf16x8*)(hr0 + ko);
      bf16x8 a1 = *(const bf16x8*)(hr1 + ko);
      const int kbx = (1024 + ko*2) ^ swz;
      bf16x8 brf = *(const bf16x8*)(wbase +         kbx);
      bf16x8 bzf = *(const bf16x8*)(wbase + 32768 + kbx);
      bf16x8 bnf = *(const bf16x8*)(wbase + 65536 + kbx);
      ar[0]  = __builtin_amdgcn_mfma_f32_16x16x32_bf16(a0, brf, ar[0],0,0,0);
      ar[1]  = __builtin_amdgcn_mfma_f32_16x16x32_bf16(a1, brf, ar[1],0,0,0);
      az[0]  = __builtin_amdgcn_mfma_f32_16x16x32_bf16(a0, bzf, az[0],0,0,0);
      az[1]  = __builtin_amdgcn_mfma_f32_16x16x32_bf16(a1, bzf, az[1],0,0,0);
      anh[0] = __builtin_amdgcn_mfma_f32_16x16x32_bf16(a0, bnf, anh[0],0,0,0);
      anh[1] = __builtin_amdgcn_mfma_f32_16x16x32_bf16(a1, bnf, anh[1],0,0,0);
    }

    // ---- epilogue: gates, h update, register max-pool
    #pragma unroll
    for (int mf=0; mf<2; ++mf){
      #pragma unroll
      for (int j=0; j<4; ++j){
        const int m = wrow + mf*16 + lkg*4 + j;
        const int b = b0 + m;
        const float rg = 1.f/(1.f + __expf(-(ar[mf][j] + br)));
        const float zg = 1.f/(1.f + __expf(-(az[mf][j] + bz)));
        const float ng = tanhf(anx[mf][j] + bnx + rg*(anh[mf][j] + bnh));
        const float hp = h32in[(size_t)b*HH + jj];
        const float hn = (1.f - zg)*ng + zg*hp;
        h32out[(size_t)b*HH + jj] = hn;
        hbout[(size_t)b*HH + jj]  = f2bf(hn);
        const float mk = mask[b*TT + tx];
        const float cand = (mk != 0.f) ? hn : -FLT_MAX;
        omax[mf][j] = fmaxf(omax[mf][j], cand);
      }
    }

    // ---- group barrier (32 WGs): release-add, relaxed poll, acquire fence
    if (t < TT-1) {
      __syncthreads();   // all WG h-stores issued & drained before leader's release
      if (tid == 0) {
        __hip_atomic_fetch_add(myctr, 1u, __ATOMIC_RELEASE, __HIP_MEMORY_SCOPE_AGENT);
        const unsigned int tgt = 32u*(unsigned)(t+1);
        while (__hip_atomic_load(myctr, __ATOMIC_RELAXED, __HIP_MEMORY_SCOPE_AGENT) < tgt)
          __builtin_amdgcn_s_sleep(4);
      }
      __syncthreads();
      __threadfence();   // acquire side: invalidate caches before reading fresh h
    }
  }

  // ---- final masked-max write: out[b][dir*H + jj]
  #pragma unroll
  for (int mf=0; mf<2; ++mf){
    #pragma unroll
    for (int j=0; j<4; ++j){
      const int b = b0 + wrow + mf*16 + lkg*4 + j;
      out[(size_t)b*(2*HH) + dir*HH + jj] = omax[mf][j];
    }
  }
}

extern "C" void kernel_launch(void* const* d_in, const int* in_sizes, int n_in,
                              void* d_out, int out_size, void* d_ws, size_t ws_size,
                              hipStream_t stream) {
  const float* x    = (const float*)d_in[0];
  const float* WihF = (const float*)d_in[1];
  const float* WhhF = (const float*)d_in[2];
  const float* bihF = (const float*)d_in[3];
  const float* bhhF = (const float*)d_in[4];
  const float* WihB = (const float*)d_in[5];
  const float* WhhB = (const float*)d_in[6];
  const float* bihB = (const float*)d_in[7];
  const float* bhhB = (const float*)d_in[8];
  float* out = (float*)d_out;

  char* ws = (char*)d_ws;
  unsigned short* xb    = (unsigned short*)(ws);              // B*T*C bf16 = 20,971,520 B
  unsigned short* wb    = (unsigned short*)(ws + 20971520);   // 4 * 786432 bf16
  unsigned short* wihFb = wb;
  unsigned short* whhFb = wb + 786432;
  unsigned short* wihBb = wb + 2*786432;
  unsigned short* whhBb = wb + 3*786432;
  float* mask = (float*)(ws + 27262976);                      // B*T floats
  float* h32  = (float*)(ws + 27344896);                      // [2dir][2buf][B][H] f32 (4MB)
  unsigned short* hb = (unsigned short*)(ws + 31539200);      // [2dir][2buf][B][H] bf16 (2MB)
  unsigned int* ctr  = (unsigned int*)(ws + 33636352);        // 8 counters, 128B stride

  prep_x_kernel<<<BB*TT/4, 256, 0, stream>>>(x, xb, mask);
  cvt_kernel<<<3072, 256, 0, stream>>>(WihF, wihFb, 786432);
  cvt_kernel<<<3072, 256, 0, stream>>>(WhhF, whhFb, 786432);
  cvt_kernel<<<3072, 256, 0, stream>>>(WihB, wihBb, 786432);
  cvt_kernel<<<3072, 256, 0, stream>>>(WhhB, whhBb, 786432);
  init_h_kernel<<<4096, 256, 0, stream>>>(h32, hb, ctr);

  gru_persist_kernel<<<256, 256, 0, stream>>>(xb, wihFb, whhFb, wihBb, whhBb,
                                              bihF, bhhF, bihB, bhhB,
                                              mask, h32, hb, out, ctr);
}

// Round 4
// 439.028 us; speedup vs baseline: 4.0273x; 4.0273x over previous
//
#include <hip/hip_runtime.h>
#include <hip/hip_bf16.h>
#include <float.h>

#define BB 512
#define TT 40
#define CC 512
#define HH 512

typedef short bf16x8 __attribute__((ext_vector_type(8)));
typedef float f32x4 __attribute__((ext_vector_type(4)));
typedef unsigned short ushortx8 __attribute__((ext_vector_type(8)));

__device__ __forceinline__ unsigned short f2bf(float f){
  union { float f; unsigned int i; } v; v.f = f;
  unsigned int r = v.i + 0x7fffu + ((v.i >> 16) & 1u);
  return (unsigned short)(r >> 16);
}

// one wave per (b,t): convert 512 floats -> bf16, compute nonzero mask (transposed [T][B])
__global__ void prep_x_kernel(const float* __restrict__ x, unsigned short* __restrict__ xb,
                              float* __restrict__ maskT){
  int w = blockIdx.x*4 + (threadIdx.x>>6);
  int lane = threadIdx.x & 63;
  const float* src = x + (size_t)w*CC + lane*8;
  f32x4 a = *(const f32x4*)(src);
  f32x4 b = *(const f32x4*)(src+4);
  ushortx8 o;
  o[0]=f2bf(a[0]); o[1]=f2bf(a[1]); o[2]=f2bf(a[2]); o[3]=f2bf(a[3]);
  o[4]=f2bf(b[0]); o[5]=f2bf(b[1]); o[6]=f2bf(b[2]); o[7]=f2bf(b[3]);
  *(ushortx8*)(xb + (size_t)w*CC + lane*8) = o;
  bool nz = (a[0]!=0.f)||(a[1]!=0.f)||(a[2]!=0.f)||(a[3]!=0.f)||
            (b[0]!=0.f)||(b[1]!=0.f)||(b[2]!=0.f)||(b[3]!=0.f);
  unsigned long long bal = __ballot(nz);
  if (lane==0){
    int b_ = w / TT, t_ = w % TT;
    maskT[t_*BB + b_] = bal ? 1.0f : 0.0f;
  }
}

__global__ void cvt_kernel(const float* __restrict__ src, unsigned short* __restrict__ dst, int n){
  int i = blockIdx.x*blockDim.x + threadIdx.x;
  if (i < n) dst[i] = f2bf(src[i]);
}

// zero bf16 h buffers (2dir x 2buf x 512 x 512) and the 8 group counters.
__global__ void init_h_kernel(unsigned short* __restrict__ hb, unsigned int* __restrict__ ctr){
  int i = blockIdx.x*blockDim.x + threadIdx.x;
  hb[i] = 0;
  if (i < 8) ctr[i*32] = 0u;
}

// Persistent GRU, normal launch, 256 WGs x 256 threads, 1 WG/CU.
// grp = bid & 7 -> (dir, 128-row b-slab); strip = bid >> 3 -> 16 h cols.
// With round-robin bid->XCD, each group's 32 WGs live on ONE XCD: the h
// recurrence closes inside one (coherent-for-itself) L2, so the inter-WG
// barrier needs NO cache maintenance: syncthreads (vmcnt drain) + relaxed
// atomic counter; h loads use volatile (sc0: bypass stale per-CU L1, hit L2).
// h fp32 carry lives in registers (same lane computes h[b][jj] every step).
__global__ __launch_bounds__(256) void gru_persist_kernel(
    const unsigned short* __restrict__ xb,
    const unsigned short* __restrict__ wihF, const unsigned short* __restrict__ whhF,
    const unsigned short* __restrict__ wihB, const unsigned short* __restrict__ whhB,
    const float* __restrict__ bihF, const float* __restrict__ bhhF,
    const float* __restrict__ bihB, const float* __restrict__ bhhB,
    const float* __restrict__ maskT,
    unsigned short* __restrict__ hb,
    float* __restrict__ out, unsigned int* __restrict__ ctr)
{
  const int bid   = blockIdx.x;
  const int grp   = bid & 7;       // XCD-local group (round-robin dispatch)
  const int strip = bid >> 3;      // 0..31
  const int dir   = grp >> 2;      // 0..1
  const int bslab = grp & 3;       // 0..3
  const int b0 = bslab * 128;
  const int n0 = strip * 16;
  unsigned int* myctr = ctr + grp*32;   // 128B-strided counters

  const unsigned short* wih = dir ? wihB : wihF;
  const unsigned short* whh = dir ? whhB : whhF;
  const float* bih = dir ? bihB : bihF;
  const float* bhh = dir ? bhhB : bhhF;

  const int tid  = threadIdx.x;
  const int lane = tid & 63;
  const int lr   = lane & 15;       // fragment row/col index
  const int lkg  = lane >> 4;       // 0..3 k-group
  const int wv   = tid >> 6;        // wave 0..3
  const int wrow = wv * 32;         // wave's first batch row within slab

  // ---- LDS weight strip: rows 0-15 = r gate, 16-31 = z, 32-47 = n; K fused [Wih|Whh]
  __shared__ __align__(16) unsigned short wlds[48 * 1024];  // 96 KB
  for (int q = tid; q < 6144; q += 256) {        // 6144 16B-chunks
    const int row = q >> 7;                      // 0..47
    const int kc  = (q & 127) * 8;               // element k 0..1023
    const int g   = row >> 4;
    const int c   = row & 15;
    const unsigned short* src =
        (kc < 512 ? wih : whh) + ((size_t)(g*HH + n0 + c))*512 + (kc & 511);
    const int kb = kc * 2;
    *(ushortx8*)((char*)wlds + row*2048 + (kb ^ ((row & 7) << 4))) =
        *(const ushortx8*)src;
  }
  __syncthreads();

  // per-lane biases for column jj
  const int jj = n0 + lr;
  const float br  = bih[jj]        + bhh[jj];
  const float bz  = bih[HH + jj]   + bhh[HH + jj];
  const float bnx = bih[2*HH + jj];
  const float bnh = bhh[2*HH + jj];

  float omax[2][4], hreg[2][4];
  #pragma unroll
  for (int mf=0; mf<2; ++mf)
    #pragma unroll
    for (int j=0; j<4; ++j){ omax[mf][j] = -FLT_MAX; hreg[mf][j] = 0.f; }

  const int swz = (lr & 7) << 4;
  const char* wbase = (const char*)wlds + lr*2048;

  for (int t = 0; t < TT; ++t) {
    const int tx = dir ? (TT-1-t) : t;
    const int bi = t & 1;
    const unsigned short* hbin = hb + (size_t)(dir*2 + bi)      * (BB*HH);
    unsigned short* hbout      = hb + (size_t)(dir*2 + (bi^1))  * (BB*HH);

    f32x4 ar[2], az[2], anx[2], anh[2];
    #pragma unroll
    for (int mf=0; mf<2; ++mf){ ar[mf]=0.f; az[mf]=0.f; anx[mf]=0.f; anh[mf]=0.f; }

    const unsigned short* xr0 = xb + ((size_t)(b0 + wrow + lr     )*TT + tx)*CC;
    const unsigned short* xr1 = xb + ((size_t)(b0 + wrow + 16 + lr)*TT + tx)*CC;

    // ---- x-part (K=0..511, no h dependency): runs while other WGs finish step t-1
    #pragma unroll
    for (int kk = 0; kk < 16; ++kk) {
      const int ko = kk*32 + lkg*8;
      bf16x8 a0 = *(const bf16x8*)(xr0 + ko);
      bf16x8 a1 = *(const bf16x8*)(xr1 + ko);
      const int kbx = (ko*2) ^ swz;
      bf16x8 brf = *(const bf16x8*)(wbase +         kbx);
      bf16x8 bzf = *(const bf16x8*)(wbase + 32768 + kbx);
      bf16x8 bnf = *(const bf16x8*)(wbase + 65536 + kbx);
      ar[0]  = __builtin_amdgcn_mfma_f32_16x16x32_bf16(a0, brf, ar[0],0,0,0);
      ar[1]  = __builtin_amdgcn_mfma_f32_16x16x32_bf16(a1, brf, ar[1],0,0,0);
      az[0]  = __builtin_amdgcn_mfma_f32_16x16x32_bf16(a0, bzf, az[0],0,0,0);
      az[1]  = __builtin_amdgcn_mfma_f32_16x16x32_bf16(a1, bzf, az[1],0,0,0);
      anx[0] = __builtin_amdgcn_mfma_f32_16x16x32_bf16(a0, bnf, anx[0],0,0,0);
      anx[1] = __builtin_amdgcn_mfma_f32_16x16x32_bf16(a1, bnf, anx[1],0,0,0);
    }

    // ---- wait for step t-1's h to be published (L2-local, no cache maintenance)
    if (t > 0) {
      if (tid == 0) {
        const unsigned int tgt = 32u*(unsigned)t;
        unsigned int spin = 0;
        while (__hip_atomic_load(myctr, __ATOMIC_RELAXED, __HIP_MEMORY_SCOPE_AGENT) < tgt
               && ++spin < (1u<<22))
          __builtin_amdgcn_s_sleep(2);
      }
      __syncthreads();
    }

    // ---- h-part (K=512..1023): volatile loads bypass L1 (sc0), read fresh L2 h
    const volatile bf16x8* hv0 = (const volatile bf16x8*)(hbin + (size_t)(b0 + wrow + lr     )*HH);
    const volatile bf16x8* hv1 = (const volatile bf16x8*)(hbin + (size_t)(b0 + wrow + 16 + lr)*HH);
    #pragma unroll
    for (int kk = 0; kk < 16; ++kk) {
      const int ki = kk*4 + lkg;          // index in bf16x8 units
      bf16x8 a0 = hv0[ki];
      bf16x8 a1 = hv1[ki];
      const int kbx = (1024 + (kk*32 + lkg*8)*2) ^ swz;
      bf16x8 brf = *(const bf16x8*)(wbase +         kbx);
      bf16x8 bzf = *(const bf16x8*)(wbase + 32768 + kbx);
      bf16x8 bnf = *(const bf16x8*)(wbase + 65536 + kbx);
      ar[0]  = __builtin_amdgcn_mfma_f32_16x16x32_bf16(a0, brf, ar[0],0,0,0);
      ar[1]  = __builtin_amdgcn_mfma_f32_16x16x32_bf16(a1, brf, ar[1],0,0,0);
      az[0]  = __builtin_amdgcn_mfma_f32_16x16x32_bf16(a0, bzf, az[0],0,0,0);
      az[1]  = __builtin_amdgcn_mfma_f32_16x16x32_bf16(a1, bzf, az[1],0,0,0);
      anh[0] = __builtin_amdgcn_mfma_f32_16x16x32_bf16(a0, bnf, anh[0],0,0,0);
      anh[1] = __builtin_amdgcn_mfma_f32_16x16x32_bf16(a1, bnf, anh[1],0,0,0);
    }

    // ---- epilogue: gates, register h carry, register max-pool, bf16 h store
    const float* mrow = maskT + tx*BB + b0 + wrow + lkg*4;
    const f32x4 mk0 = *(const f32x4*)(mrow);
    const f32x4 mk1 = *(const f32x4*)(mrow + 16);
    #pragma unroll
    for (int mf=0; mf<2; ++mf){
      const f32x4 mk = mf ? mk1 : mk0;
      #pragma unroll
      for (int j=0; j<4; ++j){
        const int m = wrow + mf*16 + lkg*4 + j;
        const int b = b0 + m;
        const float rg = 1.f/(1.f + __expf(-(ar[mf][j] + br)));
        const float zg = 1.f/(1.f + __expf(-(az[mf][j] + bz)));
        const float ng = tanhf(anx[mf][j] + bnx + rg*(anh[mf][j] + bnh));
        const float hn = (1.f - zg)*ng + zg*hreg[mf][j];
        hreg[mf][j] = hn;
        hbout[(size_t)b*HH + jj] = f2bf(hn);
        const float cand = (mk[j] != 0.f) ? hn : -FLT_MAX;
        omax[mf][j] = fmaxf(omax[mf][j], cand);
      }
    }

    // ---- publish step t's h: syncthreads drains all waves' stores to L2 (vmcnt 0),
    //      then leader bumps the group counter (relaxed; same-XCD visibility via L2/L3)
    if (t < TT-1) {
      __syncthreads();
      if (tid == 0)
        __hip_atomic_fetch_add(myctr, 1u, __ATOMIC_RELAXED, __HIP_MEMORY_SCOPE_AGENT);
    }
  }

  // ---- final masked-max write: out[b][dir*H + jj]
  #pragma unroll
  for (int mf=0; mf<2; ++mf){
    #pragma unroll
    for (int j=0; j<4; ++j){
      const int b = b0 + wrow + mf*16 + lkg*4 + j;
      out[(size_t)b*(2*HH) + dir*HH + jj] = omax[mf][j];
    }
  }
}

extern "C" void kernel_launch(void* const* d_in, const int* in_sizes, int n_in,
                              void* d_out, int out_size, void* d_ws, size_t ws_size,
                              hipStream_t stream) {
  const float* x    = (const float*)d_in[0];
  const float* WihF = (const float*)d_in[1];
  const float* WhhF = (const float*)d_in[2];
  const float* bihF = (const float*)d_in[3];
  const float* bhhF = (const float*)d_in[4];
  const float* WihB = (const float*)d_in[5];
  const float* WhhB = (const float*)d_in[6];
  const float* bihB = (const float*)d_in[7];
  const float* bhhB = (const float*)d_in[8];
  float* out = (float*)d_out;

  char* ws = (char*)d_ws;
  unsigned short* xb    = (unsigned short*)(ws);              // B*T*C bf16 = 20,971,520 B
  unsigned short* wb    = (unsigned short*)(ws + 20971520);   // 4 * 786432 bf16
  unsigned short* wihFb = wb;
  unsigned short* whhFb = wb + 786432;
  unsigned short* wihBb = wb + 2*786432;
  unsigned short* whhBb = wb + 3*786432;
  float* maskT = (float*)(ws + 27262976);                     // [T][B] floats (81920 B)
  unsigned short* hb = (unsigned short*)(ws + 27344896);      // [2dir][2buf][B][H] bf16 (2MB)
  unsigned int* ctr  = (unsigned int*)(ws + 29442048);        // 8 counters, 128B stride

  prep_x_kernel<<<BB*TT/4, 256, 0, stream>>>(x, xb, maskT);
  cvt_kernel<<<3072, 256, 0, stream>>>(WihF, wihFb, 786432);
  cvt_kernel<<<3072, 256, 0, stream>>>(WhhF, whhFb, 786432);
  cvt_kernel<<<3072, 256, 0, stream>>>(WihB, wihBb, 786432);
  cvt_kernel<<<3072, 256, 0, stream>>>(WhhB, whhBb, 786432);
  init_h_kernel<<<4096, 256, 0, stream>>>(hb, ctr);

  gru_persist_kernel<<<256, 256, 0, stream>>>(xb, wihFb, whhFb, wihBb, whhBb,
                                              bihF, bhhF, bihB, bhhB,
                                              maskT, hb, out, ctr);
}

// Round 5
// 355.663 us; speedup vs baseline: 4.9712x; 1.2344x over previous
//
#include <hip/hip_runtime.h>
#include <hip/hip_bf16.h>
#include <float.h>

#define BB 512
#define TT 40
#define CC 512
#define HH 512

typedef short bf16x8 __attribute__((ext_vector_type(8)));
typedef float f32x4 __attribute__((ext_vector_type(4)));
typedef unsigned short ushortx8 __attribute__((ext_vector_type(8)));

__device__ __forceinline__ unsigned short f2bf(float f){
  union { float f; unsigned int i; } v; v.f = f;
  unsigned int r = v.i + 0x7fffu + ((v.i >> 16) & 1u);
  return (unsigned short)(r >> 16);
}

// 16B global load bypassing L1 (sc0): h is produced by other CUs; our L1 may
// hold stale lines from 2 steps ago. asm volatile (no mem clobber) so issues
// stay in program order but everything else schedules freely around them.
__device__ __forceinline__ bf16x8 load_sc0(const unsigned short* p){
  bf16x8 r;
  asm volatile("global_load_dwordx4 %0, %1, off sc0" : "=v"(r) : "v"(p));
  return r;
}
#define WAITV(N) do { asm volatile("s_waitcnt vmcnt(" #N ")" ::: "memory"); \
                      __builtin_amdgcn_sched_barrier(0); } while(0)

__device__ __forceinline__ float fast_sigmoid(float x){
  return __builtin_amdgcn_rcpf(1.f + __expf(-x));
}
__device__ __forceinline__ float fast_tanh(float x){
  // 1 - 2/(e^{2x}+1): exact saturation both ends, ~1e-7 rel err via v_rcp
  return 1.f - 2.f*__builtin_amdgcn_rcpf(__expf(2.f*x) + 1.f);
}

// one wave per (b,t): convert 512 floats -> bf16, compute nonzero mask (transposed [T][B])
__global__ void prep_x_kernel(const float* __restrict__ x, unsigned short* __restrict__ xb,
                              float* __restrict__ maskT){
  int w = blockIdx.x*4 + (threadIdx.x>>6);
  int lane = threadIdx.x & 63;
  const float* src = x + (size_t)w*CC + lane*8;
  f32x4 a = *(const f32x4*)(src);
  f32x4 b = *(const f32x4*)(src+4);
  ushortx8 o;
  o[0]=f2bf(a[0]); o[1]=f2bf(a[1]); o[2]=f2bf(a[2]); o[3]=f2bf(a[3]);
  o[4]=f2bf(b[0]); o[5]=f2bf(b[1]); o[6]=f2bf(b[2]); o[7]=f2bf(b[3]);
  *(ushortx8*)(xb + (size_t)w*CC + lane*8) = o;
  bool nz = (a[0]!=0.f)||(a[1]!=0.f)||(a[2]!=0.f)||(a[3]!=0.f)||
            (b[0]!=0.f)||(b[1]!=0.f)||(b[2]!=0.f)||(b[3]!=0.f);
  unsigned long long bal = __ballot(nz);
  if (lane==0){
    int b_ = w / TT, t_ = w % TT;
    maskT[t_*BB + b_] = bal ? 1.0f : 0.0f;
  }
}

__global__ void cvt_kernel(const float* __restrict__ src, unsigned short* __restrict__ dst, int n){
  int i = blockIdx.x*blockDim.x + threadIdx.x;
  if (i < n) dst[i] = f2bf(src[i]);
}

// zero bf16 h buffers (2dir x 2buf x 512 x 512) and the 8 group counters.
__global__ void init_h_kernel(unsigned short* __restrict__ hb, unsigned int* __restrict__ ctr){
  int i = blockIdx.x*blockDim.x + threadIdx.x;
  hb[i] = 0;
  if (i < 8) ctr[i*32] = 0u;
}

// Persistent GRU, 256 WGs x 256 threads, 1 WG/CU, grp = bid&7 -> one XCD.
// No in-loop __syncthreads: per-WAVE self-paced barrier. Each wave, after its
// h-stores drain (vmcnt0), adds 1 to the group counter (relaxed, agent scope).
// A wave enters step t's h-part once ctr >= 128*t (32 WGs x 4 waves).
// Buffer-reuse safety: a wave's k-th add follows its step-(k-1) h reads, and a
// writer of buffer bi at step t+2 waits for 128*(t+2) adds, which includes all
// step-t reads of bi.
__global__ __launch_bounds__(256) void gru_persist_kernel(
    const unsigned short* __restrict__ xb,
    const unsigned short* __restrict__ wihF, const unsigned short* __restrict__ whhF,
    const unsigned short* __restrict__ wihB, const unsigned short* __restrict__ whhB,
    const float* __restrict__ bihF, const float* __restrict__ bhhF,
    const float* __restrict__ bihB, const float* __restrict__ bhhB,
    const float* __restrict__ maskT,
    unsigned short* __restrict__ hb,
    float* __restrict__ out, unsigned int* __restrict__ ctr)
{
  const int bid   = blockIdx.x;
  const int grp   = bid & 7;       // XCD-local group (round-robin dispatch)
  const int strip = bid >> 3;      // 0..31
  const int dir   = grp >> 2;      // 0..1
  const int bslab = grp & 3;       // 0..3
  const int b0 = bslab * 128;
  const int n0 = strip * 16;
  unsigned int* myctr = ctr + grp*32;   // 128B-strided counters

  const unsigned short* wih = dir ? wihB : wihF;
  const unsigned short* whh = dir ? whhB : whhF;
  const float* bih = dir ? bihB : bihF;
  const float* bhh = dir ? bhhB : bhhF;

  const int tid  = threadIdx.x;
  const int lane = tid & 63;
  const int lr   = lane & 15;       // fragment row/col index
  const int lkg  = lane >> 4;       // 0..3 k-group
  const int wv   = tid >> 6;        // wave 0..3
  const int wrow = wv * 32;         // wave's first batch row within slab

  // ---- LDS weight strip: rows 0-15 = r gate, 16-31 = z, 32-47 = n; K fused [Wih|Whh]
  __shared__ __align__(16) unsigned short wlds[48 * 1024];  // 96 KB
  for (int q = tid; q < 6144; q += 256) {        // 6144 16B-chunks
    const int row = q >> 7;                      // 0..47
    const int kc  = (q & 127) * 8;               // element k 0..1023
    const int g   = row >> 4;
    const int c   = row & 15;
    const unsigned short* src =
        (kc < 512 ? wih : whh) + ((size_t)(g*HH + n0 + c))*512 + (kc & 511);
    const int kb = kc * 2;
    *(ushortx8*)((char*)wlds + row*2048 + (kb ^ ((row & 7) << 4))) =
        *(const ushortx8*)src;
  }
  __syncthreads();   // only barrier in the kernel

  // per-lane biases for column jj
  const int jj = n0 + lr;
  const float br  = bih[jj]        + bhh[jj];
  const float bz  = bih[HH + jj]   + bhh[HH + jj];
  const float bnx = bih[2*HH + jj];
  const float bnh = bhh[2*HH + jj];

  float omax[2][4], hreg[2][4];
  #pragma unroll
  for (int mf=0; mf<2; ++mf)
    #pragma unroll
    for (int j=0; j<4; ++j){ omax[mf][j] = -FLT_MAX; hreg[mf][j] = 0.f; }

  const int swz = (lr & 7) << 4;
  const char* wbase = (const char*)wlds + lr*2048;

  for (int t = 0; t < TT; ++t) {
    const int tx = dir ? (TT-1-t) : t;
    const int bi = t & 1;
    const unsigned short* hbin = hb + (size_t)(dir*2 + bi)      * (BB*HH);
    unsigned short* hbout      = hb + (size_t)(dir*2 + (bi^1))  * (BB*HH);

    f32x4 ar[2], az[2], anx[2], anh[2];
    #pragma unroll
    for (int mf=0; mf<2; ++mf){ ar[mf]=0.f; az[mf]=0.f; anx[mf]=0.f; anh[mf]=0.f; }

    const unsigned short* xr0 = xb + ((size_t)(b0 + wrow + lr     )*TT + tx)*CC;
    const unsigned short* xr1 = xb + ((size_t)(b0 + wrow + 16 + lr)*TT + tx)*CC;

    // ---- x-part (K=0..511, no h dependency): overlaps other WGs' step t-1 tail
    #pragma unroll
    for (int kk = 0; kk < 16; ++kk) {
      const int ko = kk*32 + lkg*8;
      bf16x8 a0 = *(const bf16x8*)(xr0 + ko);
      bf16x8 a1 = *(const bf16x8*)(xr1 + ko);
      const int kbx = (ko*2) ^ swz;
      bf16x8 brf = *(const bf16x8*)(wbase +         kbx);
      bf16x8 bzf = *(const bf16x8*)(wbase + 32768 + kbx);
      bf16x8 bnf = *(const bf16x8*)(wbase + 65536 + kbx);
      ar[0]  = __builtin_amdgcn_mfma_f32_16x16x32_bf16(a0, brf, ar[0],0,0,0);
      ar[1]  = __builtin_amdgcn_mfma_f32_16x16x32_bf16(a1, brf, ar[1],0,0,0);
      az[0]  = __builtin_amdgcn_mfma_f32_16x16x32_bf16(a0, bzf, az[0],0,0,0);
      az[1]  = __builtin_amdgcn_mfma_f32_16x16x32_bf16(a1, bzf, az[1],0,0,0);
      anx[0] = __builtin_amdgcn_mfma_f32_16x16x32_bf16(a0, bnf, anx[0],0,0,0);
      anx[1] = __builtin_amdgcn_mfma_f32_16x16x32_bf16(a1, bnf, anx[1],0,0,0);
    }

    // ---- mask loads (no h dependency) hoisted before the poll
    const float* mrow = maskT + tx*BB + b0 + wrow + lkg*4;
    const f32x4 mk0 = *(const f32x4*)(mrow);
    const f32x4 mk1 = *(const f32x4*)(mrow + 16);

    // ---- self-paced wait: all lanes poll (wave-uniform address, one fetch/wave)
    if (t > 0) {
      const unsigned int tgt = 128u*(unsigned)t;
      unsigned int spin = 0;
      while (__hip_atomic_load(myctr, __ATOMIC_RELAXED, __HIP_MEMORY_SCOPE_AGENT) < tgt
             && ++spin < (1u<<24))
        __builtin_amdgcn_s_sleep(1);
    }

    // drain mask/x loads so vmcnt counting below is exact
    WAITV(0);

    // ---- h-part (K=512..1023): sc0 asm loads, 1-kk-ahead prefetch
    const unsigned short* hr0 = hbin + (size_t)(b0 + wrow + lr     )*HH;
    const unsigned short* hr1 = hbin + (size_t)(b0 + wrow + 16 + lr)*HH;
    bf16x8 c0 = load_sc0(hr0 + lkg*8);
    bf16x8 c1 = load_sc0(hr1 + lkg*8);
    #pragma unroll
    for (int kk = 0; kk < 16; ++kk) {
      const int ko = kk*32 + lkg*8;
      bf16x8 p0, p1;
      if (kk < 15) { p0 = load_sc0(hr0 + ko + 32); p1 = load_sc0(hr1 + ko + 32); }
      const int kbx = (1024 + ko*2) ^ swz;
      bf16x8 brf = *(const bf16x8*)(wbase +         kbx);
      bf16x8 bzf = *(const bf16x8*)(wbase + 32768 + kbx);
      bf16x8 bnf = *(const bf16x8*)(wbase + 65536 + kbx);
      if (kk < 15) { WAITV(2); } else { WAITV(0); }
      ar[0]  = __builtin_amdgcn_mfma_f32_16x16x32_bf16(c0, brf, ar[0],0,0,0);
      ar[1]  = __builtin_amdgcn_mfma_f32_16x16x32_bf16(c1, brf, ar[1],0,0,0);
      az[0]  = __builtin_amdgcn_mfma_f32_16x16x32_bf16(c0, bzf, az[0],0,0,0);
      az[1]  = __builtin_amdgcn_mfma_f32_16x16x32_bf16(c1, bzf, az[1],0,0,0);
      anh[0] = __builtin_amdgcn_mfma_f32_16x16x32_bf16(c0, bnf, anh[0],0,0,0);
      anh[1] = __builtin_amdgcn_mfma_f32_16x16x32_bf16(c1, bnf, anh[1],0,0,0);
      if (kk < 15) { c0 = p0; c1 = p1; }
    }

    // ---- epilogue: gates (fast exp/rcp), register h carry, register max-pool
    #pragma unroll
    for (int mf=0; mf<2; ++mf){
      const f32x4 mk = mf ? mk1 : mk0;
      #pragma unroll
      for (int j=0; j<4; ++j){
        const int m = wrow + mf*16 + lkg*4 + j;
        const int b = b0 + m;
        const float rg = fast_sigmoid(ar[mf][j] + br);
        const float zg = fast_sigmoid(az[mf][j] + bz);
        const float ng = fast_tanh(anx[mf][j] + bnx + rg*(anh[mf][j] + bnh));
        const float hn = (1.f - zg)*ng + zg*hreg[mf][j];
        hreg[mf][j] = hn;
        hbout[(size_t)b*HH + jj] = f2bf(hn);
        const float cand = (mk[j] != 0.f) ? hn : -FLT_MAX;
        omax[mf][j] = fmaxf(omax[mf][j], cand);
      }
    }

    // ---- per-wave publish: own stores drained -> one relaxed add
    if (t < TT-1) {
      WAITV(0);
      if (lane == 0)
        __hip_atomic_fetch_add(myctr, 1u, __ATOMIC_RELAXED, __HIP_MEMORY_SCOPE_AGENT);
    }
  }

  // ---- final masked-max write: out[b][dir*H + jj]
  #pragma unroll
  for (int mf=0; mf<2; ++mf){
    #pragma unroll
    for (int j=0; j<4; ++j){
      const int b = b0 + wrow + mf*16 + lkg*4 + j;
      out[(size_t)b*(2*HH) + dir*HH + jj] = omax[mf][j];
    }
  }
}

extern "C" void kernel_launch(void* const* d_in, const int* in_sizes, int n_in,
                              void* d_out, int out_size, void* d_ws, size_t ws_size,
                              hipStream_t stream) {
  const float* x    = (const float*)d_in[0];
  const float* WihF = (const float*)d_in[1];
  const float* WhhF = (const float*)d_in[2];
  const float* bihF = (const float*)d_in[3];
  const float* bhhF = (const float*)d_in[4];
  const float* WihB = (const float*)d_in[5];
  const float* WhhB = (const float*)d_in[6];
  const float* bihB = (const float*)d_in[7];
  const float* bhhB = (const float*)d_in[8];
  float* out = (float*)d_out;

  char* ws = (char*)d_ws;
  unsigned short* xb    = (unsigned short*)(ws);              // B*T*C bf16 = 20,971,520 B
  unsigned short* wb    = (unsigned short*)(ws + 20971520);   // 4 * 786432 bf16
  unsigned short* wihFb = wb;
  unsigned short* whhFb = wb + 786432;
  unsigned short* wihBb = wb + 2*786432;
  unsigned short* whhBb = wb + 3*786432;
  float* maskT = (float*)(ws + 27262976);                     // [T][B] floats (81920 B)
  unsigned short* hb = (unsigned short*)(ws + 27344896);      // [2dir][2buf][B][H] bf16 (2MB)
  unsigned int* ctr  = (unsigned int*)(ws + 29442048);        // 8 counters, 128B stride

  prep_x_kernel<<<BB*TT/4, 256, 0, stream>>>(x, xb, maskT);
  cvt_kernel<<<3072, 256, 0, stream>>>(WihF, wihFb, 786432);
  cvt_kernel<<<3072, 256, 0, stream>>>(WhhF, whhFb, 786432);
  cvt_kernel<<<3072, 256, 0, stream>>>(WihB, wihBb, 786432);
  cvt_kernel<<<3072, 256, 0, stream>>>(WhhB, whhBb, 786432);
  init_h_kernel<<<4096, 256, 0, stream>>>(hb, ctr);

  gru_persist_kernel<<<256, 256, 0, stream>>>(xb, wihFb, whhFb, wihBb, whhBb,
                                              bihF, bhhF, bihB, bhhB,
                                              maskT, hb, out, ctr);
}